// Round 8
// baseline (1575.152 us; speedup 1.0000x reference)
//
#include <hip/hip_runtime.h>
#include <hip/hip_fp16.h>

#define DIM 512
#define N_ITERS 10
#define ROWS_PER_WAVE 6
#define TPB 256
// waves/block = 4; blocks = ceil(16384 / 24) = 683; capacity at launch_bounds(256,4)
// is 4 blocks/CU * 256 CU = 1024 >> 683, and even at 3 blocks/CU (768) it fits.

typedef float floatx2 __attribute__((ext_vector_type(2)));

__device__ __forceinline__ unsigned int pack2h(float lo, float hi) {
    __half2 h = __float22half2_rn(make_float2(lo, hi));
    return *reinterpret_cast<unsigned int*>(&h);
}
__device__ __forceinline__ float2 unpack2h(unsigned int u) {
    return __half22float2(*reinterpret_cast<__half2*>(&u));
}
__device__ __forceinline__ unsigned int pack4f8(float f0, float f1, float f2, float f3) {
    int v = 0;
    v = __builtin_amdgcn_cvt_pk_fp8_f32(f0, f1, v, false);
    v = __builtin_amdgcn_cvt_pk_fp8_f32(f2, f3, v, true);
    return (unsigned int)v;
}

// consts[0]=a, consts[1]=b, consts[2]=1/(4s^2); also zeroes barrier words
__global__ void consts_kernel(const float* alpha, const float* beta,
                              const float* sigma, float* consts, int* barrier_ws) {
    if (threadIdx.x == 0 && blockIdx.x == 0) {
        float a = expf(alpha[0]);
        float b = expf(beta[0]);
        float s = expf(sigma[0]);
        consts[0] = a;
        consts[1] = b;
        consts[2] = 1.0f / (4.0f * s * s);
        barrier_ws[0] = 0;   // arrival counter
        barrier_ws[1] = 0;   // sense/epoch
    }
}

// one wave per row: x8=fp8(x), xn8=fp8(x/||x||), xb16=fp16(x*b)
__global__ void __launch_bounds__(256)
rownorm_kernel(const float* __restrict__ x,
               const float* __restrict__ consts,
               unsigned int* __restrict__ x8,
               unsigned int* __restrict__ xn8,
               unsigned short* __restrict__ xb16, int n) {
    int wid = (blockIdx.x * blockDim.x + threadIdx.x) >> 6;
    int lane = threadIdx.x & 63;
    if (wid >= n) return;
    const float4* p = (const float4*)(x + (size_t)wid * DIM) + lane * 2;
    float4 u = p[0];
    float4 v = p[1];
    float s = u.x*u.x + u.y*u.y + u.z*u.z + u.w*u.w
            + v.x*v.x + v.y*v.y + v.z*v.z + v.w*v.w;
    uint2 q;
    q.x = pack4f8(u.x, u.y, u.z, u.w);
    q.y = pack4f8(v.x, v.y, v.z, v.w);
    *(uint2*)(x8 + (size_t)wid * (DIM / 4) + lane * 2) = q;
    float b = consts[1];
    uint4 hb;
    hb.x = pack2h(u.x * b, u.y * b); hb.y = pack2h(u.z * b, u.w * b);
    hb.z = pack2h(v.x * b, v.y * b); hb.w = pack2h(v.z * b, v.w * b);
    *(uint4*)(xb16 + (size_t)wid * DIM + lane * 8) = hb;
    #pragma unroll
    for (int m = 32; m >= 1; m >>= 1) s += __shfl_xor(s, m, 64);
    float inr = rsqrtf(fmaxf(s, 1e-12f));
    uint2 qn;
    qn.x = pack4f8(u.x * inr, u.y * inr, u.z * inr, u.w * inr);
    qn.y = pack4f8(v.x * inr, v.y * inr, v.z * inr, v.w * inr);
    *(uint2*)(xn8 + (size_t)wid * (DIM / 4) + lane * 2) = qn;
}

__global__ void rowptr_kernel(const int* __restrict__ erow, int nnz,
                              int* __restrict__ rstart, int n) {
    int r = blockIdx.x * blockDim.x + threadIdx.x;
    if (r > n) return;
    int lo = 0, hi = nnz;
    while (lo < hi) {
        int mid = (lo + hi) >> 1;
        if (erow[mid] < r) lo = mid + 1; else hi = mid;
    }
    rstart[r] = lo;
}

__device__ __forceinline__ float dot8f8(const float* A, uint2 h) {
    floatx2 p0 = __builtin_amdgcn_cvt_pk_f32_fp8((int)h.x, false);
    floatx2 p1 = __builtin_amdgcn_cvt_pk_f32_fp8((int)h.x, true);
    floatx2 p2 = __builtin_amdgcn_cvt_pk_f32_fp8((int)h.y, false);
    floatx2 p3 = __builtin_amdgcn_cvt_pk_f32_fp8((int)h.y, true);
    return A[0]*p0.x + A[1]*p0.y + A[2]*p1.x + A[3]*p1.y
         + A[4]*p2.x + A[5]*p2.y + A[6]*p3.x + A[7]*p3.y;
}

// one wave per ROW over fp8 normalized rows; 4-deep pipeline; fused inv_denom
__global__ void __launch_bounds__(256)
edge_row_kernel(const unsigned int* __restrict__ xn8,
                const float* __restrict__ eval_,
                const int* __restrict__ ecol,
                const int* __restrict__ rstart,
                const float* __restrict__ consts,
                float* __restrict__ sup, float* __restrict__ inv_denom, int n) {
    int row = (blockIdx.x * blockDim.x + threadIdx.x) >> 6;
    int lane = threadIdx.x & 63;
    if (row >= n) return;
    uint2 hr = *(const uint2*)(xn8 + (size_t)row * (DIM / 4) + lane * 2);
    float A[8];
    {
        floatx2 p0 = __builtin_amdgcn_cvt_pk_f32_fp8((int)hr.x, false);
        floatx2 p1 = __builtin_amdgcn_cvt_pk_f32_fp8((int)hr.x, true);
        floatx2 p2 = __builtin_amdgcn_cvt_pk_f32_fp8((int)hr.y, false);
        floatx2 p3 = __builtin_amdgcn_cvt_pk_f32_fp8((int)hr.y, true);
        A[0]=p0.x; A[1]=p0.y; A[2]=p1.x; A[3]=p1.y;
        A[4]=p2.x; A[5]=p2.y; A[6]=p3.x; A[7]=p3.y;
    }
    float c2 = consts[2];
    int rs = rstart[row], re = rstart[row + 1];
    float norm_acc = 0.0f;
    int e = rs;
    for (; e + 3 < re; e += 4) {
        int c[4]; uint2 h[4]; float s[4];
        #pragma unroll
        for (int j = 0; j < 4; ++j) c[j] = ecol[e + j];
        #pragma unroll
        for (int j = 0; j < 4; ++j)
            h[j] = *(const uint2*)(xn8 + (size_t)c[j] * (DIM / 4) + lane * 2);
        #pragma unroll
        for (int j = 0; j < 4; ++j) s[j] = dot8f8(A, h[j]);
        #pragma unroll
        for (int m = 32; m >= 1; m >>= 1) {
            #pragma unroll
            for (int j = 0; j < 4; ++j) s[j] += __shfl_xor(s[j], m, 64);
        }
        #pragma unroll
        for (int j = 0; j < 4; ++j) {
            float sim = (row == c[j]) ? 0.0f : s[j];
            float sp = eval_[e + j] * expf(sim * c2);
            norm_acc += sp;
            if (lane == 0) sup[e + j] = sp;
        }
    }
    for (; e < re; ++e) {
        int c0 = ecol[e];
        uint2 h0 = *(const uint2*)(xn8 + (size_t)c0 * (DIM / 4) + lane * 2);
        float s0 = dot8f8(A, h0);
        #pragma unroll
        for (int m = 32; m >= 1; m >>= 1) s0 += __shfl_xor(s0, m, 64);
        float sim0 = (row == c0) ? 0.0f : s0;
        float sp0 = eval_[e] * expf(sim0 * c2);
        norm_acc += sp0;
        if (lane == 0) sup[e] = sp0;
    }
    if (lane == 0) {
        float a = consts[0], b = consts[1];
        inv_denom[row] = 1.0f / (b + norm_acc * a + a);
    }
}

// device-scope grid barrier: monotonic epoch counter + sense word
__device__ __forceinline__ void grid_barrier(int* cnt, int* sense, int nblocks, int epoch) {
    __syncthreads();
    if (threadIdx.x == 0) {
        __threadfence();
        int old = __hip_atomic_fetch_add(cnt, 1, __ATOMIC_ACQ_REL, __HIP_MEMORY_SCOPE_AGENT);
        if (old == nblocks * (epoch + 1) - 1) {
            __hip_atomic_store(sense, epoch + 1, __ATOMIC_RELEASE, __HIP_MEMORY_SCOPE_AGENT);
        } else {
            while (__hip_atomic_load(sense, __ATOMIC_ACQUIRE, __HIP_MEMORY_SCOPE_AGENT) < epoch + 1) {
                __builtin_amdgcn_s_sleep(8);
            }
        }
    }
    __syncthreads();
}

#define ACCF8(hh, ww)                                                              \
    do {                                                                           \
        floatx2 p_;                                                                \
        p_ = __builtin_amdgcn_cvt_pk_f32_fp8((int)(hh).x, false); acc0 += (ww)*p_.x; acc1 += (ww)*p_.y; \
        p_ = __builtin_amdgcn_cvt_pk_f32_fp8((int)(hh).x, true);  acc2 += (ww)*p_.x; acc3 += (ww)*p_.y; \
        p_ = __builtin_amdgcn_cvt_pk_f32_fp8((int)(hh).y, false); acc4 += (ww)*p_.x; acc5 += (ww)*p_.y; \
        p_ = __builtin_amdgcn_cvt_pk_f32_fp8((int)(hh).y, true);  acc6 += (ww)*p_.x; acc7 += (ww)*p_.y; \
    } while (0)

// persistent kernel, ordinary launch: 4 waves/block, 6 rows/wave, iterate in fp32 regs
__global__ void __launch_bounds__(TPB, 4)
persist_kernel(const float* __restrict__ x,
               const float* __restrict__ consts,
               const float* __restrict__ inv_denom,
               const float* __restrict__ sup,
               const int* __restrict__ ecol,
               const int* __restrict__ rstart,
               const unsigned short* __restrict__ xb16,
               unsigned int* __restrict__ bufA,   // fp8(x) on entry
               unsigned int* __restrict__ bufB,
               float* __restrict__ out_f32,
               int* __restrict__ bar, int n, int nblocks) {
    int warp = threadIdx.x >> 6;
    int lane = threadIdx.x & 63;
    int wid = blockIdx.x * 4 + warp;
    int row0 = wid * ROWS_PER_WAVE;
    const size_t loff8 = lane * 2;
    float a = consts[0];
    int* cnt = bar;
    int* sense = bar + 1;

    float cur[ROWS_PER_WAVE][8];
    float invd[ROWS_PER_WAVE];
    int rs_[ROWS_PER_WAVE], re_[ROWS_PER_WAVE];
    int nrows = n - row0;
    if (nrows > ROWS_PER_WAVE) nrows = ROWS_PER_WAVE;
    if (nrows < 0) nrows = 0;
    for (int i = 0; i < nrows; ++i) {
        int row = row0 + i;
        const float4* p = (const float4*)(x + (size_t)row * DIM) + lane * 2;
        float4 u = p[0], v = p[1];
        cur[i][0]=u.x; cur[i][1]=u.y; cur[i][2]=u.z; cur[i][3]=u.w;
        cur[i][4]=v.x; cur[i][5]=v.y; cur[i][6]=v.z; cur[i][7]=v.w;
        invd[i] = inv_denom[row];
        rs_[i] = rstart[row];
        re_[i] = rstart[row + 1];
    }

    for (int it = 0; it < N_ITERS; ++it) {
        const unsigned int* prev8 = (it & 1) ? bufB : bufA;
        unsigned int* next8       = (it & 1) ? bufA : bufB;
        bool is_last = (it == N_ITERS - 1);
        for (int ri = 0; ri < nrows; ++ri) {
            int row = row0 + ri;
            int rs = rs_[ri], re = re_[ri];
            float acc0=0.f,acc1=0.f,acc2=0.f,acc3=0.f,acc4=0.f,acc5=0.f,acc6=0.f,acc7=0.f;
            int e = rs;
            for (; e + 7 < re; e += 8) {
                int c[8]; float w[8]; uint2 h[8];
                #pragma unroll
                for (int j = 0; j < 8; ++j) { c[j] = ecol[e + j]; w[j] = sup[e + j]; }
                #pragma unroll
                for (int j = 0; j < 8; ++j)
                    h[j] = *(const uint2*)(prev8 + (size_t)c[j] * (DIM / 4) + loff8);
                #pragma unroll
                for (int j = 0; j < 8; ++j) ACCF8(h[j], w[j]);
            }
            for (; e + 1 < re; e += 2) {
                int c0 = ecol[e], c1 = ecol[e + 1];
                float w0 = sup[e], w1 = sup[e + 1];
                uint2 h0 = *(const uint2*)(prev8 + (size_t)c0 * (DIM / 4) + loff8);
                uint2 h1 = *(const uint2*)(prev8 + (size_t)c1 * (DIM / 4) + loff8);
                ACCF8(h0, w0); ACCF8(h1, w1);
            }
            if (e < re) {
                int c0 = ecol[e]; float w0 = sup[e];
                uint2 h0 = *(const uint2*)(prev8 + (size_t)c0 * (DIM / 4) + loff8);
                ACCF8(h0, w0);
            }
            uint4 hx = *(const uint4*)(xb16 + (size_t)row * DIM + lane * 8);
            float2 x0 = unpack2h(hx.x), x1 = unpack2h(hx.y);
            float2 x2 = unpack2h(hx.z), x3 = unpack2h(hx.w);
            float invdv = invd[ri];
            float r0 = (x0.x + (acc0 + cur[ri][0]) * a) * invdv;
            float r1 = (x0.y + (acc1 + cur[ri][1]) * a) * invdv;
            float r2 = (x1.x + (acc2 + cur[ri][2]) * a) * invdv;
            float r3 = (x1.y + (acc3 + cur[ri][3]) * a) * invdv;
            float r4 = (x2.x + (acc4 + cur[ri][4]) * a) * invdv;
            float r5 = (x2.y + (acc5 + cur[ri][5]) * a) * invdv;
            float r6 = (x3.x + (acc6 + cur[ri][6]) * a) * invdv;
            float r7 = (x3.y + (acc7 + cur[ri][7]) * a) * invdv;
            if (!is_last) {
                uint2 q;
                q.x = pack4f8(r0, r1, r2, r3);
                q.y = pack4f8(r4, r5, r6, r7);
                *(uint2*)(next8 + (size_t)row * (DIM / 4) + loff8) = q;
            } else {
                float4* o = (float4*)(out_f32 + (size_t)row * DIM) + lane * 2;
                o[0] = make_float4(r0, r1, r2, r3);
                o[1] = make_float4(r4, r5, r6, r7);
            }
            cur[ri][0]=r0; cur[ri][1]=r1; cur[ri][2]=r2; cur[ri][3]=r3;
            cur[ri][4]=r4; cur[ri][5]=r5; cur[ri][6]=r6; cur[ri][7]=r7;
        }
        if (!is_last) grid_barrier(cnt, sense, nblocks, it);
    }
}

extern "C" void kernel_launch(void* const* d_in, const int* in_sizes, int n_in,
                              void* d_out, int out_size, void* d_ws, size_t ws_size,
                              hipStream_t stream) {
    const float* x     = (const float*)d_in[0];
    const float* alpha = (const float*)d_in[1];
    const float* beta  = (const float*)d_in[2];
    const float* sigma = (const float*)d_in[3];
    const float* eval_ = (const float*)d_in[4];
    const int* erow = (const int*)d_in[5];
    const int* ecol = (const int*)d_in[6];

    const int n   = in_sizes[0] / DIM;   // 16384
    const int nnz = in_sizes[4];         // 163840

    float* ws        = (float*)d_ws;
    float* consts    = ws;                            // 64 floats
    int*   bar       = (int*)(ws + 64);               // 2 ints (+pad to 64)
    float* inv_denom = ws + 128;                      // n
    int*   rstart    = (int*)(inv_denom + n);         // n+1 (+pad)
    float* sup       = (float*)(rstart + n + 64);     // nnz
    unsigned short* xb16 = (unsigned short*)(sup + nnz);        // n*DIM fp16 (16 MB)
    unsigned int* xn8  = (unsigned int*)(xb16 + (size_t)n * DIM); // 8 MB
    unsigned int* bufA = xn8 + (size_t)n * (DIM / 4);           // 8 MB (init fp8(x))
    unsigned int* bufB = bufA + (size_t)n * (DIM / 4);          // 8 MB
    float* out_f32 = (float*)d_out;

    const int waves_needed = (n + ROWS_PER_WAVE - 1) / ROWS_PER_WAVE;  // 2731
    const int nblocks = (waves_needed + 3) / 4;                        // 683

    consts_kernel<<<1, 64, 0, stream>>>(alpha, beta, sigma, consts, bar);
    rownorm_kernel<<<(n * 64) / 256, 256, 0, stream>>>(x, consts, bufA, xn8, xb16, n);
    rowptr_kernel<<<(n + 256) / 256, 256, 0, stream>>>(erow, nnz, rstart, n);
    edge_row_kernel<<<(n * 64) / 256, 256, 0, stream>>>(xn8, eval_, ecol,
                                                        rstart, consts,
                                                        sup, inv_denom, n);
    persist_kernel<<<nblocks, TPB, 0, stream>>>(x, consts, inv_denom, sup, ecol,
                                                rstart, xb16, bufA, bufB,
                                                out_f32, bar, n, nblocks);
}

// Round 9
// 1138.135 us; speedup vs baseline: 1.3840x; 1.3840x over previous
//
#include <hip/hip_runtime.h>
#include <hip/hip_fp16.h>

#define DIM 512
#define N_ITERS 10
#define ROWS_PER_WAVE 8
#define TPB 256
// waves/block = 4; 16384 rows / 8 = 2048 waves = 512 blocks.
// __launch_bounds__(256,2) -> VGPR cap 256, LDS 0 -> 2 blocks/CU guaranteed
// -> 512 co-resident blocks == grid size; barrier is deadlock-free.

typedef float floatx2 __attribute__((ext_vector_type(2)));

__device__ __forceinline__ unsigned int pack2h(float lo, float hi) {
    __half2 h = __float22half2_rn(make_float2(lo, hi));
    return *reinterpret_cast<unsigned int*>(&h);
}
__device__ __forceinline__ float2 unpack2h(unsigned int u) {
    return __half22float2(*reinterpret_cast<__half2*>(&u));
}
__device__ __forceinline__ unsigned int pack4f8(float f0, float f1, float f2, float f3) {
    int v = 0;
    v = __builtin_amdgcn_cvt_pk_fp8_f32(f0, f1, v, false);
    v = __builtin_amdgcn_cvt_pk_fp8_f32(f2, f3, v, true);
    return (unsigned int)v;
}

// consts[0]=a, consts[1]=b, consts[2]=1/(4s^2); also zeroes barrier words
__global__ void consts_kernel(const float* alpha, const float* beta,
                              const float* sigma, float* consts, int* barrier_ws) {
    if (threadIdx.x == 0 && blockIdx.x == 0) {
        float a = expf(alpha[0]);
        float b = expf(beta[0]);
        float s = expf(sigma[0]);
        consts[0] = a;
        consts[1] = b;
        consts[2] = 1.0f / (4.0f * s * s);
        barrier_ws[0] = 0;   // arrival counter
        barrier_ws[1] = 0;   // sense/epoch
    }
}

// one wave per row: x8=fp8(x), xn8=fp8(x/||x||), xb16=fp16(x*b)
__global__ void __launch_bounds__(256)
rownorm_kernel(const float* __restrict__ x,
               const float* __restrict__ consts,
               unsigned int* __restrict__ x8,
               unsigned int* __restrict__ xn8,
               unsigned short* __restrict__ xb16, int n) {
    int wid = (blockIdx.x * blockDim.x + threadIdx.x) >> 6;
    int lane = threadIdx.x & 63;
    if (wid >= n) return;
    const float4* p = (const float4*)(x + (size_t)wid * DIM) + lane * 2;
    float4 u = p[0];
    float4 v = p[1];
    float s = u.x*u.x + u.y*u.y + u.z*u.z + u.w*u.w
            + v.x*v.x + v.y*v.y + v.z*v.z + v.w*v.w;
    uint2 q;
    q.x = pack4f8(u.x, u.y, u.z, u.w);
    q.y = pack4f8(v.x, v.y, v.z, v.w);
    *(uint2*)(x8 + (size_t)wid * (DIM / 4) + lane * 2) = q;
    float b = consts[1];
    uint4 hb;
    hb.x = pack2h(u.x * b, u.y * b); hb.y = pack2h(u.z * b, u.w * b);
    hb.z = pack2h(v.x * b, v.y * b); hb.w = pack2h(v.z * b, v.w * b);
    *(uint4*)(xb16 + (size_t)wid * DIM + lane * 8) = hb;
    #pragma unroll
    for (int m = 32; m >= 1; m >>= 1) s += __shfl_xor(s, m, 64);
    float inr = rsqrtf(fmaxf(s, 1e-12f));
    uint2 qn;
    qn.x = pack4f8(u.x * inr, u.y * inr, u.z * inr, u.w * inr);
    qn.y = pack4f8(v.x * inr, v.y * inr, v.z * inr, v.w * inr);
    *(uint2*)(xn8 + (size_t)wid * (DIM / 4) + lane * 2) = qn;
}

__global__ void rowptr_kernel(const int* __restrict__ erow, int nnz,
                              int* __restrict__ rstart, int n) {
    int r = blockIdx.x * blockDim.x + threadIdx.x;
    if (r > n) return;
    int lo = 0, hi = nnz;
    while (lo < hi) {
        int mid = (lo + hi) >> 1;
        if (erow[mid] < r) lo = mid + 1; else hi = mid;
    }
    rstart[r] = lo;
}

__device__ __forceinline__ float dot8f8(const float* A, uint2 h) {
    floatx2 p0 = __builtin_amdgcn_cvt_pk_f32_fp8((int)h.x, false);
    floatx2 p1 = __builtin_amdgcn_cvt_pk_f32_fp8((int)h.x, true);
    floatx2 p2 = __builtin_amdgcn_cvt_pk_f32_fp8((int)h.y, false);
    floatx2 p3 = __builtin_amdgcn_cvt_pk_f32_fp8((int)h.y, true);
    return A[0]*p0.x + A[1]*p0.y + A[2]*p1.x + A[3]*p1.y
         + A[4]*p2.x + A[5]*p2.y + A[6]*p3.x + A[7]*p3.y;
}

// one wave per ROW over fp8 normalized rows; 4-deep pipeline; fused inv_denom
__global__ void __launch_bounds__(256)
edge_row_kernel(const unsigned int* __restrict__ xn8,
                const float* __restrict__ eval_,
                const int* __restrict__ ecol,
                const int* __restrict__ rstart,
                const float* __restrict__ consts,
                float* __restrict__ sup, float* __restrict__ inv_denom, int n) {
    int row = (blockIdx.x * blockDim.x + threadIdx.x) >> 6;
    int lane = threadIdx.x & 63;
    if (row >= n) return;
    uint2 hr = *(const uint2*)(xn8 + (size_t)row * (DIM / 4) + lane * 2);
    float A[8];
    {
        floatx2 p0 = __builtin_amdgcn_cvt_pk_f32_fp8((int)hr.x, false);
        floatx2 p1 = __builtin_amdgcn_cvt_pk_f32_fp8((int)hr.x, true);
        floatx2 p2 = __builtin_amdgcn_cvt_pk_f32_fp8((int)hr.y, false);
        floatx2 p3 = __builtin_amdgcn_cvt_pk_f32_fp8((int)hr.y, true);
        A[0]=p0.x; A[1]=p0.y; A[2]=p1.x; A[3]=p1.y;
        A[4]=p2.x; A[5]=p2.y; A[6]=p3.x; A[7]=p3.y;
    }
    float c2 = consts[2];
    int rs = rstart[row], re = rstart[row + 1];
    float norm_acc = 0.0f;
    int e = rs;
    for (; e + 3 < re; e += 4) {
        int c[4]; uint2 h[4]; float s[4];
        #pragma unroll
        for (int j = 0; j < 4; ++j) c[j] = ecol[e + j];
        #pragma unroll
        for (int j = 0; j < 4; ++j)
            h[j] = *(const uint2*)(xn8 + (size_t)c[j] * (DIM / 4) + lane * 2);
        #pragma unroll
        for (int j = 0; j < 4; ++j) s[j] = dot8f8(A, h[j]);
        #pragma unroll
        for (int m = 32; m >= 1; m >>= 1) {
            #pragma unroll
            for (int j = 0; j < 4; ++j) s[j] += __shfl_xor(s[j], m, 64);
        }
        #pragma unroll
        for (int j = 0; j < 4; ++j) {
            float sim = (row == c[j]) ? 0.0f : s[j];
            float sp = eval_[e + j] * expf(sim * c2);
            norm_acc += sp;
            if (lane == 0) sup[e + j] = sp;
        }
    }
    for (; e < re; ++e) {
        int c0 = ecol[e];
        uint2 h0 = *(const uint2*)(xn8 + (size_t)c0 * (DIM / 4) + lane * 2);
        float s0 = dot8f8(A, h0);
        #pragma unroll
        for (int m = 32; m >= 1; m >>= 1) s0 += __shfl_xor(s0, m, 64);
        float sim0 = (row == c0) ? 0.0f : s0;
        float sp0 = eval_[e] * expf(sim0 * c2);
        norm_acc += sp0;
        if (lane == 0) sup[e] = sp0;
    }
    if (lane == 0) {
        float a = consts[0], b = consts[1];
        inv_denom[row] = 1.0f / (b + norm_acc * a + a);
    }
}

// device-scope grid barrier: monotonic epoch counter + sense word (proven in R8)
__device__ __forceinline__ void grid_barrier(int* cnt, int* sense, int nblocks, int epoch) {
    __syncthreads();
    if (threadIdx.x == 0) {
        __threadfence();
        int old = __hip_atomic_fetch_add(cnt, 1, __ATOMIC_ACQ_REL, __HIP_MEMORY_SCOPE_AGENT);
        if (old == nblocks * (epoch + 1) - 1) {
            __hip_atomic_store(sense, epoch + 1, __ATOMIC_RELEASE, __HIP_MEMORY_SCOPE_AGENT);
        } else {
            while (__hip_atomic_load(sense, __ATOMIC_ACQUIRE, __HIP_MEMORY_SCOPE_AGENT) < epoch + 1) {
                __builtin_amdgcn_s_sleep(8);
            }
        }
    }
    __syncthreads();
}

#define ACCF8(hh, ww)                                                              \
    do {                                                                           \
        floatx2 p_;                                                                \
        p_ = __builtin_amdgcn_cvt_pk_f32_fp8((int)(hh).x, false); acc0 += (ww)*p_.x; acc1 += (ww)*p_.y; \
        p_ = __builtin_amdgcn_cvt_pk_f32_fp8((int)(hh).x, true);  acc2 += (ww)*p_.x; acc3 += (ww)*p_.y; \
        p_ = __builtin_amdgcn_cvt_pk_f32_fp8((int)(hh).y, false); acc4 += (ww)*p_.x; acc5 += (ww)*p_.y; \
        p_ = __builtin_amdgcn_cvt_pk_f32_fp8((int)(hh).y, true);  acc6 += (ww)*p_.x; acc7 += (ww)*p_.y; \
    } while (0)

// persistent kernel: 4 waves/block, 8 rows/wave, iterate in fp32 regs.
// ROW LOOPS ARE FULLY UNROLLED (constant indices) so cur[][] stays in VGPRs —
// R8's runtime-indexed version spilled all state to scratch (479 MB writes).
__global__ void __launch_bounds__(TPB, 2)
persist_kernel(const float* __restrict__ x,
               const float* __restrict__ consts,
               const float* __restrict__ inv_denom,
               const float* __restrict__ sup,
               const int* __restrict__ ecol,
               const int* __restrict__ rstart,
               const unsigned short* __restrict__ xb16,
               unsigned int* __restrict__ bufA,   // fp8(x) on entry
               unsigned int* __restrict__ bufB,
               float* __restrict__ out_f32,
               int* __restrict__ bar, int n, int nblocks) {
    int warp = threadIdx.x >> 6;
    int lane = threadIdx.x & 63;
    int wid = blockIdx.x * 4 + warp;          // 0..2047
    int row0 = wid * ROWS_PER_WAVE;
    const size_t loff8 = lane * 2;
    float a = consts[0];
    int* cnt = bar;
    int* sense = bar + 1;

    float cur[ROWS_PER_WAVE][8];
    float invd[ROWS_PER_WAVE];
    int rs_[ROWS_PER_WAVE], re_[ROWS_PER_WAVE];
    #pragma unroll
    for (int i = 0; i < ROWS_PER_WAVE; ++i) {
        int row = row0 + i;
        bool act = row < n;
        const float4* p = (const float4*)(x + (size_t)(act ? row : 0) * DIM) + lane * 2;
        float4 u = p[0], v = p[1];
        cur[i][0]=u.x; cur[i][1]=u.y; cur[i][2]=u.z; cur[i][3]=u.w;
        cur[i][4]=v.x; cur[i][5]=v.y; cur[i][6]=v.z; cur[i][7]=v.w;
        invd[i] = act ? inv_denom[row] : 0.0f;
        rs_[i] = act ? rstart[row] : 0;
        re_[i] = act ? rstart[row + 1] : 0;
    }

    for (int it = 0; it < N_ITERS; ++it) {
        const unsigned int* prev8 = (it & 1) ? bufB : bufA;
        unsigned int* next8       = (it & 1) ? bufA : bufB;
        bool is_last = (it == N_ITERS - 1);
        #pragma unroll
        for (int ri = 0; ri < ROWS_PER_WAVE; ++ri) {
            int row = row0 + ri;
            if (row >= n) continue;
            int rs = rs_[ri], re = re_[ri];
            float acc0=0.f,acc1=0.f,acc2=0.f,acc3=0.f,acc4=0.f,acc5=0.f,acc6=0.f,acc7=0.f;
            int e = rs;
            for (; e + 7 < re; e += 8) {
                int c[8]; float w[8]; uint2 h[8];
                #pragma unroll
                for (int j = 0; j < 8; ++j) { c[j] = ecol[e + j]; w[j] = sup[e + j]; }
                #pragma unroll
                for (int j = 0; j < 8; ++j)
                    h[j] = *(const uint2*)(prev8 + (size_t)c[j] * (DIM / 4) + loff8);
                #pragma unroll
                for (int j = 0; j < 8; ++j) ACCF8(h[j], w[j]);
            }
            for (; e + 1 < re; e += 2) {
                int c0 = ecol[e], c1 = ecol[e + 1];
                float w0 = sup[e], w1 = sup[e + 1];
                uint2 h0 = *(const uint2*)(prev8 + (size_t)c0 * (DIM / 4) + loff8);
                uint2 h1 = *(const uint2*)(prev8 + (size_t)c1 * (DIM / 4) + loff8);
                ACCF8(h0, w0); ACCF8(h1, w1);
            }
            if (e < re) {
                int c0 = ecol[e]; float w0 = sup[e];
                uint2 h0 = *(const uint2*)(prev8 + (size_t)c0 * (DIM / 4) + loff8);
                ACCF8(h0, w0);
            }
            uint4 hx = *(const uint4*)(xb16 + (size_t)row * DIM + lane * 8);
            float2 x0 = unpack2h(hx.x), x1 = unpack2h(hx.y);
            float2 x2 = unpack2h(hx.z), x3 = unpack2h(hx.w);
            float invdv = invd[ri];
            float r0 = (x0.x + (acc0 + cur[ri][0]) * a) * invdv;
            float r1 = (x0.y + (acc1 + cur[ri][1]) * a) * invdv;
            float r2 = (x1.x + (acc2 + cur[ri][2]) * a) * invdv;
            float r3 = (x1.y + (acc3 + cur[ri][3]) * a) * invdv;
            float r4 = (x2.x + (acc4 + cur[ri][4]) * a) * invdv;
            float r5 = (x2.y + (acc5 + cur[ri][5]) * a) * invdv;
            float r6 = (x3.x + (acc6 + cur[ri][6]) * a) * invdv;
            float r7 = (x3.y + (acc7 + cur[ri][7]) * a) * invdv;
            if (!is_last) {
                uint2 q;
                q.x = pack4f8(r0, r1, r2, r3);
                q.y = pack4f8(r4, r5, r6, r7);
                *(uint2*)(next8 + (size_t)row * (DIM / 4) + loff8) = q;
            } else {
                float4* o = (float4*)(out_f32 + (size_t)row * DIM) + lane * 2;
                o[0] = make_float4(r0, r1, r2, r3);
                o[1] = make_float4(r4, r5, r6, r7);
            }
            cur[ri][0]=r0; cur[ri][1]=r1; cur[ri][2]=r2; cur[ri][3]=r3;
            cur[ri][4]=r4; cur[ri][5]=r5; cur[ri][6]=r6; cur[ri][7]=r7;
        }
        if (!is_last) grid_barrier(cnt, sense, nblocks, it);
    }
}

extern "C" void kernel_launch(void* const* d_in, const int* in_sizes, int n_in,
                              void* d_out, int out_size, void* d_ws, size_t ws_size,
                              hipStream_t stream) {
    const float* x     = (const float*)d_in[0];
    const float* alpha = (const float*)d_in[1];
    const float* beta  = (const float*)d_in[2];
    const float* sigma = (const float*)d_in[3];
    const float* eval_ = (const float*)d_in[4];
    const int* erow = (const int*)d_in[5];
    const int* ecol = (const int*)d_in[6];

    const int n   = in_sizes[0] / DIM;   // 16384
    const int nnz = in_sizes[4];         // 163840

    float* ws        = (float*)d_ws;
    float* consts    = ws;                            // 64 floats
    int*   bar       = (int*)(ws + 64);               // 2 ints (+pad to 64)
    float* inv_denom = ws + 128;                      // n
    int*   rstart    = (int*)(inv_denom + n);         // n+1 (+pad)
    float* sup       = (float*)(rstart + n + 64);     // nnz
    unsigned short* xb16 = (unsigned short*)(sup + nnz);          // 16 MB
    unsigned int* xn8  = (unsigned int*)(xb16 + (size_t)n * DIM); // 8 MB
    unsigned int* bufA = xn8 + (size_t)n * (DIM / 4);             // 8 MB (init fp8(x))
    unsigned int* bufB = bufA + (size_t)n * (DIM / 4);            // 8 MB
    float* out_f32 = (float*)d_out;

    const int waves_needed = (n + ROWS_PER_WAVE - 1) / ROWS_PER_WAVE;  // 2048
    const int nblocks = (waves_needed + 3) / 4;                        // 512

    consts_kernel<<<1, 64, 0, stream>>>(alpha, beta, sigma, consts, bar);
    rownorm_kernel<<<(n * 64) / 256, 256, 0, stream>>>(x, consts, bufA, xn8, xb16, n);
    rowptr_kernel<<<(n + 256) / 256, 256, 0, stream>>>(erow, nnz, rstart, n);
    edge_row_kernel<<<(n * 64) / 256, 256, 0, stream>>>(xn8, eval_, ecol,
                                                        rstart, consts,
                                                        sup, inv_denom, n);
    persist_kernel<<<nblocks, TPB, 0, stream>>>(x, consts, inv_denom, sup, ecol,
                                                rstart, xb16, bufA, bufB,
                                                out_f32, bar, n, nblocks);
}

// Round 10
// 337.401 us; speedup vs baseline: 4.6685x; 3.3732x over previous
//
#include <hip/hip_runtime.h>
#include <hip/hip_fp16.h>

#define DIM 512
#define N_ITERS 10

typedef float floatx2 __attribute__((ext_vector_type(2)));

__device__ __forceinline__ unsigned int pack2h(float lo, float hi) {
    __half2 h = __float22half2_rn(make_float2(lo, hi));
    return *reinterpret_cast<unsigned int*>(&h);
}
__device__ __forceinline__ float2 unpack2h(unsigned int u) {
    return __half22float2(*reinterpret_cast<__half2*>(&u));
}
__device__ __forceinline__ unsigned int pack4f8(float f0, float f1, float f2, float f3) {
    int v = 0;
    v = __builtin_amdgcn_cvt_pk_fp8_f32(f0, f1, v, false);
    v = __builtin_amdgcn_cvt_pk_fp8_f32(f2, f3, v, true);
    return (unsigned int)v;
}

// consts[0]=a, consts[1]=b, consts[2]=1/(4s^2); also writes rstart[n]=nnz
__global__ void consts_kernel(const float* alpha, const float* beta,
                              const float* sigma, float* consts,
                              int* rstart, int n, int nnz) {
    if (threadIdx.x == 0 && blockIdx.x == 0) {
        float a = expf(alpha[0]);
        float b = expf(beta[0]);
        float s = expf(sigma[0]);
        consts[0] = a;
        consts[1] = b;
        consts[2] = 1.0f / (4.0f * s * s);
        rstart[n] = nnz;
    }
}

// one wave per row: xh16=fp16(x), x8=fp8(x), xn8=fp8(x/||x||), xb16=fp16(x*b);
// lane 0 also computes rstart[row] (binary search on sorted erow) — replaces
// the separate rowptr dispatch.
__global__ void __launch_bounds__(256)
rownorm_kernel(const float* __restrict__ x,
               const float* __restrict__ consts,
               unsigned short* __restrict__ xh16,
               unsigned int* __restrict__ x8,
               unsigned int* __restrict__ xn8,
               unsigned short* __restrict__ xb16,
               const int* __restrict__ erow, int nnz,
               int* __restrict__ rstart, int n) {
    int wid = (blockIdx.x * blockDim.x + threadIdx.x) >> 6;
    int lane = threadIdx.x & 63;
    if (wid >= n) return;
    const size_t base = (size_t)wid * DIM + lane * 8;
    const float4* p = (const float4*)(x + base);
    float4 u = p[0];
    float4 v = p[1];
    if (lane == 0) {
        int lo = 0, hi = nnz;
        while (lo < hi) {
            int mid = (lo + hi) >> 1;
            if (erow[mid] < wid) lo = mid + 1; else hi = mid;
        }
        rstart[wid] = lo;
    }
    float s = u.x*u.x + u.y*u.y + u.z*u.z + u.w*u.w
            + v.x*v.x + v.y*v.y + v.z*v.z + v.w*v.w;
    uint4 h;
    h.x = pack2h(u.x, u.y); h.y = pack2h(u.z, u.w);
    h.z = pack2h(v.x, v.y); h.w = pack2h(v.z, v.w);
    *(uint4*)(xh16 + base) = h;
    uint2 q;
    q.x = pack4f8(u.x, u.y, u.z, u.w);
    q.y = pack4f8(v.x, v.y, v.z, v.w);
    *(uint2*)(x8 + (size_t)wid * (DIM / 4) + lane * 2) = q;
    float b = consts[1];
    uint4 hb;
    hb.x = pack2h(u.x * b, u.y * b); hb.y = pack2h(u.z * b, u.w * b);
    hb.z = pack2h(v.x * b, v.y * b); hb.w = pack2h(v.z * b, v.w * b);
    *(uint4*)(xb16 + base) = hb;
    #pragma unroll
    for (int m = 32; m >= 1; m >>= 1) s += __shfl_xor(s, m, 64);
    float inr = rsqrtf(fmaxf(s, 1e-12f));
    uint2 qn;
    qn.x = pack4f8(u.x * inr, u.y * inr, u.z * inr, u.w * inr);
    qn.y = pack4f8(v.x * inr, v.y * inr, v.z * inr, v.w * inr);
    *(uint2*)(xn8 + (size_t)wid * (DIM / 4) + lane * 2) = qn;
}

__device__ __forceinline__ float dot8f8(const float* A, uint2 h) {
    floatx2 p0 = __builtin_amdgcn_cvt_pk_f32_fp8((int)h.x, false);
    floatx2 p1 = __builtin_amdgcn_cvt_pk_f32_fp8((int)h.x, true);
    floatx2 p2 = __builtin_amdgcn_cvt_pk_f32_fp8((int)h.y, false);
    floatx2 p3 = __builtin_amdgcn_cvt_pk_f32_fp8((int)h.y, true);
    return A[0]*p0.x + A[1]*p0.y + A[2]*p1.x + A[3]*p1.y
         + A[4]*p2.x + A[5]*p2.y + A[6]*p3.x + A[7]*p3.y;
}

// one wave per ROW over fp8 normalized rows; 8-deep pipeline; fused inv_denom.
// Writes packed (col, sup) per edge for the iter kernels.
__global__ void __launch_bounds__(256)
edge_row_kernel(const unsigned int* __restrict__ xn8,
                const float* __restrict__ eval_,
                const int* __restrict__ ecol,
                const int* __restrict__ rstart,
                const float* __restrict__ consts,
                uint2* __restrict__ epk, float* __restrict__ inv_denom, int n) {
    int row = (blockIdx.x * blockDim.x + threadIdx.x) >> 6;
    int lane = threadIdx.x & 63;
    if (row >= n) return;
    uint2 hr = *(const uint2*)(xn8 + (size_t)row * (DIM / 4) + lane * 2);
    float A[8];
    {
        floatx2 p0 = __builtin_amdgcn_cvt_pk_f32_fp8((int)hr.x, false);
        floatx2 p1 = __builtin_amdgcn_cvt_pk_f32_fp8((int)hr.x, true);
        floatx2 p2 = __builtin_amdgcn_cvt_pk_f32_fp8((int)hr.y, false);
        floatx2 p3 = __builtin_amdgcn_cvt_pk_f32_fp8((int)hr.y, true);
        A[0]=p0.x; A[1]=p0.y; A[2]=p1.x; A[3]=p1.y;
        A[4]=p2.x; A[5]=p2.y; A[6]=p3.x; A[7]=p3.y;
    }
    float c2 = consts[2];
    int rs = rstart[row], re = rstart[row + 1];
    float norm_acc = 0.0f;
    int e = rs;
    for (; e + 7 < re; e += 8) {
        int c[8]; uint2 h[8]; float s[8]; float ev[8];
        #pragma unroll
        for (int j = 0; j < 8; ++j) c[j] = ecol[e + j];
        #pragma unroll
        for (int j = 0; j < 8; ++j) ev[j] = eval_[e + j];
        #pragma unroll
        for (int j = 0; j < 8; ++j)
            h[j] = *(const uint2*)(xn8 + (size_t)c[j] * (DIM / 4) + lane * 2);
        #pragma unroll
        for (int j = 0; j < 8; ++j) s[j] = dot8f8(A, h[j]);
        #pragma unroll
        for (int m = 32; m >= 1; m >>= 1) {
            #pragma unroll
            for (int j = 0; j < 8; ++j) s[j] += __shfl_xor(s[j], m, 64);
        }
        #pragma unroll
        for (int j = 0; j < 8; ++j) {
            float sim = (row == c[j]) ? 0.0f : s[j];
            float sp = ev[j] * expf(sim * c2);
            norm_acc += sp;
            if (lane == 0) epk[e + j] = make_uint2((unsigned int)c[j], __float_as_uint(sp));
        }
    }
    for (; e + 1 < re; e += 2) {
        int c0 = ecol[e], c1 = ecol[e + 1];
        float ev0 = eval_[e], ev1 = eval_[e + 1];
        uint2 h0 = *(const uint2*)(xn8 + (size_t)c0 * (DIM / 4) + lane * 2);
        uint2 h1 = *(const uint2*)(xn8 + (size_t)c1 * (DIM / 4) + lane * 2);
        float s0 = dot8f8(A, h0);
        float s1 = dot8f8(A, h1);
        #pragma unroll
        for (int m = 32; m >= 1; m >>= 1) {
            s0 += __shfl_xor(s0, m, 64);
            s1 += __shfl_xor(s1, m, 64);
        }
        float sim0 = (row == c0) ? 0.0f : s0;
        float sim1 = (row == c1) ? 0.0f : s1;
        float sp0 = ev0 * expf(sim0 * c2);
        float sp1 = ev1 * expf(sim1 * c2);
        norm_acc += sp0 + sp1;
        if (lane == 0) {
            epk[e]     = make_uint2((unsigned int)c0, __float_as_uint(sp0));
            epk[e + 1] = make_uint2((unsigned int)c1, __float_as_uint(sp1));
        }
    }
    if (e < re) {
        int c0 = ecol[e];
        uint2 h0 = *(const uint2*)(xn8 + (size_t)c0 * (DIM / 4) + lane * 2);
        float s0 = dot8f8(A, h0);
        #pragma unroll
        for (int m = 32; m >= 1; m >>= 1) s0 += __shfl_xor(s0, m, 64);
        float sim0 = (row == c0) ? 0.0f : s0;
        float sp0 = eval_[e] * expf(sim0 * c2);
        norm_acc += sp0;
        if (lane == 0) epk[e] = make_uint2((unsigned int)c0, __float_as_uint(sp0));
    }
    if (lane == 0) {
        float a = consts[0], b = consts[1];
        inv_denom[row] = 1.0f / (b + norm_acc * a + a);
    }
}

#define ACCF8(hh, ww)                                                              \
    do {                                                                           \
        floatx2 p_;                                                                \
        p_ = __builtin_amdgcn_cvt_pk_f32_fp8((int)(hh).x, false); acc0 += (ww)*p_.x; acc1 += (ww)*p_.y; \
        p_ = __builtin_amdgcn_cvt_pk_f32_fp8((int)(hh).x, true);  acc2 += (ww)*p_.x; acc3 += (ww)*p_.y; \
        p_ = __builtin_amdgcn_cvt_pk_f32_fp8((int)(hh).y, false); acc4 += (ww)*p_.x; acc5 += (ww)*p_.y; \
        p_ = __builtin_amdgcn_cvt_pk_f32_fp8((int)(hh).y, true);  acc6 += (ww)*p_.x; acc7 += (ww)*p_.y; \
    } while (0)

// one wave per row; lane owns cols 8L..8L+7; gathers fp8, self/epilogue fp16
__global__ void __launch_bounds__(256)
iter_kernel(const unsigned short* __restrict__ prev16,
            const unsigned int* __restrict__ prev8,
            unsigned short* __restrict__ next16,
            unsigned int* __restrict__ next8,
            float* __restrict__ out_f32, int last,
            const float* __restrict__ consts, const float* __restrict__ inv_denom,
            const uint2* __restrict__ epk,
            const int* __restrict__ rstart,
            const unsigned short* __restrict__ xbh, int n) {
    int row = (blockIdx.x * blockDim.x + threadIdx.x) >> 6;
    int lane = threadIdx.x & 63;
    if (row >= n) return;
    float a = consts[0];
    float inv_d = inv_denom[row];
    int rs = rstart[row], re = rstart[row + 1];
    const size_t loff16 = lane * 8;
    const size_t base16 = (size_t)row * DIM + loff16;
    const size_t loff8 = lane * 2;
    // hoist the streaming self/xb loads so they overlap the gather chain
    uint4 hs = *(const uint4*)(prev16 + base16);
    uint4 hx = *(const uint4*)(xbh + base16);
    float acc0 = 0.f, acc1 = 0.f, acc2 = 0.f, acc3 = 0.f;
    float acc4 = 0.f, acc5 = 0.f, acc6 = 0.f, acc7 = 0.f;
    int e = rs;
    for (; e + 7 < re; e += 8) {
        uint2 m[8]; uint2 h[8];
        #pragma unroll
        for (int j = 0; j < 8; ++j) m[j] = epk[e + j];
        #pragma unroll
        for (int j = 0; j < 8; ++j)
            h[j] = *(const uint2*)(prev8 + (size_t)m[j].x * (DIM / 4) + loff8);
        #pragma unroll
        for (int j = 0; j < 8; ++j) ACCF8(h[j], __uint_as_float(m[j].y));
    }
    for (; e + 1 < re; e += 2) {
        uint2 m0 = epk[e], m1 = epk[e + 1];
        uint2 h0 = *(const uint2*)(prev8 + (size_t)m0.x * (DIM / 4) + loff8);
        uint2 h1 = *(const uint2*)(prev8 + (size_t)m1.x * (DIM / 4) + loff8);
        ACCF8(h0, __uint_as_float(m0.y));
        ACCF8(h1, __uint_as_float(m1.y));
    }
    if (e < re) {
        uint2 m0 = epk[e];
        uint2 h0 = *(const uint2*)(prev8 + (size_t)m0.x * (DIM / 4) + loff8);
        ACCF8(h0, __uint_as_float(m0.y));
    }
    float2 s0 = unpack2h(hs.x), s1 = unpack2h(hs.y);
    float2 s2 = unpack2h(hs.z), s3 = unpack2h(hs.w);
    float2 x0 = unpack2h(hx.x), x1 = unpack2h(hx.y);
    float2 x2 = unpack2h(hx.z), x3 = unpack2h(hx.w);
    float r0 = (x0.x + (acc0 + s0.x) * a) * inv_d;
    float r1 = (x0.y + (acc1 + s0.y) * a) * inv_d;
    float r2 = (x1.x + (acc2 + s1.x) * a) * inv_d;
    float r3 = (x1.y + (acc3 + s1.y) * a) * inv_d;
    float r4 = (x2.x + (acc4 + s2.x) * a) * inv_d;
    float r5 = (x2.y + (acc5 + s2.y) * a) * inv_d;
    float r6 = (x3.x + (acc6 + s3.x) * a) * inv_d;
    float r7 = (x3.y + (acc7 + s3.y) * a) * inv_d;
    if (last) {
        float4* o = (float4*)(out_f32 + base16);
        o[0] = make_float4(r0, r1, r2, r3);
        o[1] = make_float4(r4, r5, r6, r7);
    } else {
        uint4 ho;
        ho.x = pack2h(r0, r1); ho.y = pack2h(r2, r3);
        ho.z = pack2h(r4, r5); ho.w = pack2h(r6, r7);
        *(uint4*)(next16 + base16) = ho;
        uint2 q;
        q.x = pack4f8(r0, r1, r2, r3);
        q.y = pack4f8(r4, r5, r6, r7);
        *(uint2*)(next8 + (size_t)row * (DIM / 4) + loff8) = q;
    }
}

extern "C" void kernel_launch(void* const* d_in, const int* in_sizes, int n_in,
                              void* d_out, int out_size, void* d_ws, size_t ws_size,
                              hipStream_t stream) {
    const float* x     = (const float*)d_in[0];
    const float* alpha = (const float*)d_in[1];
    const float* beta  = (const float*)d_in[2];
    const float* sigma = (const float*)d_in[3];
    const float* eval_ = (const float*)d_in[4];
    const int* erow = (const int*)d_in[5];
    const int* ecol = (const int*)d_in[6];

    const int n   = in_sizes[0] / DIM;   // 16384
    const int nnz = in_sizes[4];         // 163840

    float* ws        = (float*)d_ws;
    float* consts    = ws;                            // 64 floats
    float* inv_denom = ws + 64;                       // n
    int*   rstart    = (int*)(inv_denom + n);         // n+1 (+pad)
    uint2* epk       = (uint2*)(rstart + n + 64);     // nnz * 8 B (aligned: offsets even)
    unsigned short* xbh   = (unsigned short*)(epk + nnz);         // 16 MB
    unsigned short* bufB16= xbh + (size_t)n * DIM;                // 16 MB
    unsigned int*   xn8   = (unsigned int*)(bufB16 + (size_t)n * DIM); // 8 MB
    unsigned int*   bufA8 = xn8 + (size_t)n * (DIM / 4);          // 8 MB (init fp8(x))
    unsigned int*   bufB8 = bufA8 + (size_t)n * (DIM / 4);        // 8 MB
    unsigned short* bufA16 = (unsigned short*)d_out;              // first 16 MB of d_out
    float* out_f32 = (float*)d_out;

    consts_kernel<<<1, 64, 0, stream>>>(alpha, beta, sigma, consts, rstart, n, nnz);
    rownorm_kernel<<<(n * 64) / 256, 256, 0, stream>>>(x, consts, bufA16, bufA8, xn8,
                                                       xbh, erow, nnz, rstart, n);
    edge_row_kernel<<<(n * 64) / 256, 256, 0, stream>>>(xn8, eval_, ecol,
                                                        rstart, consts,
                                                        epk, inv_denom, n);

    // it0: A(x)->B, it1: B->A, ..., it8: A->B, it9: B->d_out (fp32)
    for (int it = 0; it < N_ITERS; ++it) {
        const unsigned short* prev16 = (it & 1) ? bufB16 : bufA16;
        const unsigned int*   prev8  = (it & 1) ? bufB8  : bufA8;
        unsigned short* next16 = (it & 1) ? bufA16 : bufB16;
        unsigned int*   next8  = (it & 1) ? bufA8  : bufB8;
        int last = (it == N_ITERS - 1) ? 1 : 0;
        iter_kernel<<<(n * 64) / 256, 256, 0, stream>>>(prev16, prev8, next16, next8,
                                                        out_f32, last,
                                                        consts, inv_denom, epk,
                                                        rstart, xbh, n);
    }
}